// Round 19
// baseline (166.701 us; speedup 1.0000x reference)
//
#include <hip/hip_runtime.h>
#include <math.h>

// Problem dims (fixed)
#define B_   128
#define L_   256
#define H_   128
#define H2_  256
#define VS_  256

__device__ __forceinline__ float fma4(float4 a, float4 b, float acc) {
    acc = fmaf(a.x, b.x, acc);
    acc = fmaf(a.y, b.y, acc);
    acc = fmaf(a.z, b.z, acc);
    acc = fmaf(a.w, b.w, acc);
    return acc;
}

template <int CTRL>
__device__ __forceinline__ float dpp_add(float x) {
    int y = __builtin_amdgcn_update_dpp(0, __float_as_int(x), CTRL, 0xf, 0xf, true);
    return x + __int_as_float(y);
}
// 16-lane butterfly sum (valid in all 16 lanes of each DPP row):
//   xor1, xor2 via quad_perm; then row_half_mirror (acts as xor4 on
//   quad-uniform values) and row_mirror (acts as xor8 on half-uniform).
__device__ __forceinline__ float group16_sum(float x) {
    x = dpp_add<0xB1>(x);    // quad_perm [1,0,3,2]  (xor1)
    x = dpp_add<0x4E>(x);    // quad_perm [2,3,0,1]  (xor2)
    x = dpp_add<0x141>(x);   // row_half_mirror      (xor4 for quad-uniform)
    x = dpp_add<0x140>(x);   // row_mirror           (xor8 for half-uniform)
    return x;
}

// ---------------------------------------------------------------------------
// Kernel 1: per-VOCAB fused FFN (R11/R18, measured): F[v] = Wk(LN(e+FFN(e))).
// ---------------------------------------------------------------------------
__global__ __launch_bounds__(256) void k_vffn(
    const float* __restrict__ embed,
    const float* __restrict__ W1, const float* __restrict__ b1,
    const float* __restrict__ W2, const float* __restrict__ b2,
    const float* __restrict__ gamma, const float* __restrict__ beta,
    const float* __restrict__ Wk, float* __restrict__ Fout)
{
    __shared__ float sh_h[4][128];
    __shared__ float sh_y[4][256];

    const int tid  = threadIdx.x;
    const int lane = tid & 63;
    const int r    = tid >> 6;
    const int v    = blockIdx.x * 4 + r;

    const float4* embed4 = (const float4*)embed;
    const float4* W1_4   = (const float4*)W1;
    const float4* W2_4   = (const float4*)W2;
    const float4* Wk_4   = (const float4*)Wk;

    if (lane < 32)
        *(float4*)&sh_h[r][lane * 4] = embed4[v * 32 + lane];
    __syncthreads();

    #pragma unroll
    for (int jj = 0; jj < 4; ++jj) {
        int j = jj * 64 + lane;
        const float4* wrow = W1_4 + j * 32;
        float acc = 0.f;
        #pragma unroll
        for (int c4 = 0; c4 < 32; ++c4)
            acc = fma4(*(const float4*)&sh_h[r][c4 * 4], wrow[c4], acc);
        sh_y[r][j] = fmaxf(acc + b1[j], 0.f);
    }
    __syncthreads();

    float xv[4];
    #pragma unroll
    for (int cc = 0; cc < 4; ++cc) {
        int c  = cc * 32 + (lane & 31);
        int hf = lane >> 5;
        const float4* wrow = W2_4 + c * 64 + hf * 32;
        float acc = 0.f;
        #pragma unroll
        for (int j4 = 0; j4 < 32; ++j4)
            acc = fma4(*(const float4*)&sh_y[r][(hf * 32 + j4) * 4], wrow[j4], acc);
        acc += __shfl_xor(acc, 32);
        xv[cc] = acc;
    }
    if (lane < 32) {
        #pragma unroll
        for (int cc = 0; cc < 4; ++cc) {
            int c = cc * 32 + lane;
            sh_h[r][c] = sh_h[r][c] + xv[cc] + b2[c];
        }
    }
    __syncthreads();

    {
        float2 x2 = *(const float2*)&sh_h[r][lane * 2];
        float s  = x2.x + x2.y;
        float s2 = x2.x * x2.x + x2.y * x2.y;
        s  += __shfl_xor(s, 1);  s  += __shfl_xor(s, 2);  s  += __shfl_xor(s, 4);
        s  += __shfl_xor(s, 8);  s  += __shfl_xor(s, 16); s  += __shfl_xor(s, 32);
        s2 += __shfl_xor(s2, 1); s2 += __shfl_xor(s2, 2); s2 += __shfl_xor(s2, 4);
        s2 += __shfl_xor(s2, 8); s2 += __shfl_xor(s2, 16); s2 += __shfl_xor(s2, 32);
        float mu   = s * (1.f / 128.f);
        float var  = s2 * (1.f / 128.f) - mu * mu;
        float rstd = 1.f / sqrtf(var + 1e-5f);
        float2 g2  = *(const float2*)&gamma[lane * 2];
        float2 be2 = *(const float2*)&beta[lane * 2];
        float2 o;
        o.x = (x2.x - mu) * rstd * g2.x + be2.x;
        o.y = (x2.y - mu) * rstd * g2.y + be2.y;
        *(float2*)&sh_h[r][lane * 2] = o;
    }
    __syncthreads();

    #pragma unroll
    for (int kk = 0; kk < 2; ++kk) {
        int k = kk * 64 + lane;
        const float4* wrow = Wk_4 + k * 32;
        float acc = 0.f;
        #pragma unroll
        for (int c4 = 0; c4 < 32; ++c4)
            acc = fma4(*(const float4*)&sh_h[r][c4 * 4], wrow[c4], acc);
        Fout[v * 128 + k] = acc;
    }
}

// ---------------------------------------------------------------------------
// Kernel 2: gated delta-rule scan — 4 rows x 8 cols per thread.
//   512 thr: cg = lane&15 (cols cg*8..+7), rg = w*4 + (lane>>4) (rows rg*4..+3).
//   Row-group = 16 consecutive lanes of ONE wave -> matvec dot reduces
//   fully in-wave (group16_sum); e2 = 2 DPP (16-uniform values).
//   k rows stored PERMUTED: float4 pos u*16+cg holds cols cg*8+u*4..+3
//   (refills & kself reads <=2-way bank conflict). Refill = 2 b128/thread
//   (16 KB/step block-wide, was 64 KB). Gate-decoupled matvec + counted
//   lgkmcnt barrier, exact R18 algebra. Epilogue: fused out-projection.
// ---------------------------------------------------------------------------
__global__ __launch_bounds__(512) void k_scan(
    const int* __restrict__ seq, const float* __restrict__ Fbuf,
    const float* __restrict__ Wr, const float* __restrict__ br,
    const float* __restrict__ Wo, const float* __restrict__ bo,
    float* __restrict__ out)
{
    extern __shared__ float smem_f[];
    float4* shk4  = (float4*)smem_f;          // [256][32] float4 (permuted rows)
    float*  rna   = smem_f + 32768;           // [256]
    float*  thr   = rna + 256;                // [256]
    float*  d01   = thr + 256;                // [256]
    float*  red_f = d01 + 256;                // [2][8]
    float*  rd_   = red_f + 16;               // [128] readout
    float*  r2_   = rd_ + 128;                // [128] hidden of out-proj

    const int tid  = threadIdx.x;
    const int lane = tid & 63;
    const int w    = tid >> 6;        // wave id 0..7
    const int cg   = lane & 15;       // col group (8 cols)
    const int rg   = w * 4 + (lane >> 4);    // row group 0..31 (4 rows)
    const int b    = blockIdx.x;
    const float4* F4 = (const float4*)Fbuf;
    const int* seqb = seq + b * 256;
    const int kspos = ((rg & 1) * 16) | (rg >> 1);  // float4 pos of cols rg*4..+3

    // ---- prologue 1: gather all 256 k vectors (permuted row layout) ----
    for (int f = tid; f < 8192; f += 512) {
        int p = f & 31;
        int c4 = ((p & 15) * 2) | (p >> 4);   // pos u*16+cg <- F col-chunk cg*2+u
        shk4[f] = F4[(size_t)seqb[f >> 5] * 32 + c4];
    }
    __syncthreads();

    // ---- prologue 2: per-row norms + neighbor dots (order-agnostic sums) ----
    {
        int rr = tid >> 4, cc = tid & 15;
        for (int it = 0; it < 8; ++it) {
            int t  = it * 32 + rr;
            int tn = (t < 255) ? t + 1 : 255;
            float4 a0 = shk4[t  * 32 + cc], a1 = shk4[t  * 32 + 16 + cc];
            float4 b0 = shk4[tn * 32 + cc], b1 = shk4[tn * 32 + 16 + cc];
            float n2p = fma4(a1, a1, fma4(a0, a0, 0.f));
            float cp  = fma4(a1, b1, fma4(a0, b0, 0.f));
            n2p += __shfl_xor(n2p, 1); n2p += __shfl_xor(n2p, 2);
            n2p += __shfl_xor(n2p, 4); n2p += __shfl_xor(n2p, 8);
            cp  += __shfl_xor(cp, 1);  cp  += __shfl_xor(cp, 2);
            cp  += __shfl_xor(cp, 4);  cp  += __shfl_xor(cp, 8);
            if (cc == 0) {
                rna[t] = 1.f / fmaxf(sqrtf(n2p), 1e-12f);
                thr[t] = 0.16f * n2p;
                d01[t] = cp;
            }
        }
    }

    // ---- M slice (4 rows x 8 cols), k buffers, err_0 ----
    float4 m[4][2];
    #pragma unroll
    for (int r = 0; r < 4; ++r) {
        m[r][0] = make_float4(0.f, 0.f, 0.f, 0.f);
        m[r][1] = make_float4(0.f, 0.f, 0.f, 0.f);
    }
    float4 kbE[2], kbO[2];
    kbE[0] = shk4[cg];        kbE[1] = shk4[16 + cg];        // k_0 chunk
    kbO[0] = shk4[32 + cg];   kbO[1] = shk4[32 + 16 + cg];   // k_1 chunk
    float4 errR = shk4[kspos];                               // err_0 rows rg*4..+3
    {
        float s = fmaf(errR.x, errR.x, fmaf(errR.y, errR.y,
                  fmaf(errR.z, errR.z, errR.w * errR.w)));
        s = dpp_add<0x142>(s);   // row_bcast:15
        s = dpp_add<0x143>(s);   // row_bcast:31 -> lane63 = wave total
        if (lane == 63) red_f[w] = s;    // parity-0 slots
    }
    __syncthreads();

#define REGION(T, KU, KM)                                                       \
  {                                                                             \
    const int t_ = (T);                                                         \
    float rnaT = rna[t_], rnaN = rna[t_ + 1];                                   \
    float thrT = thr[t_], d01T = d01[t_];                                       \
    float4 ksN = shk4[(t_ + 1) * 32 + kspos];   /* k_{t+1}[rows rg*4..+3] */    \
    float4 ra = ((const float4*)red_f)[(t_ & 1) * 2];                           \
    float4 rb = ((const float4*)red_f)[(t_ & 1) * 2 + 1];                       \
    /* gate-independent matvec with M_{t-1} (in-wave 16-lane reduce) */         \
    float p0 = fma4(m[0][1], KM[1], fma4(m[0][0], KM[0], 0.f));                 \
    float p1 = fma4(m[1][1], KM[1], fma4(m[1][0], KM[0], 0.f));                 \
    float p2 = fma4(m[2][1], KM[1], fma4(m[2][0], KM[0], 0.f));                 \
    float p3 = fma4(m[3][1], KM[1], fma4(m[3][0], KM[0], 0.f));                 \
    p0 = group16_sum(p0); p1 = group16_sum(p1);                                 \
    p2 = group16_sum(p2); p3 = group16_sum(p3);                                 \
    float E2 = ((ra.x + ra.y) + (ra.z + ra.w)) +                                \
               ((rb.x + rb.y) + (rb.z + rb.w));                                 \
    float gf = (E2 >= thrT) ? rnaT : 0.f;                                       \
    float a0 = gf * errR.x, a1 = gf * errR.y;                                   \
    float a2 = gf * errR.z, a3 = gf * errR.w;                                   \
    float4 errN;                                                                \
    errN.x = fmaf(-rnaN, fmaf(a0, d01T, p0), ksN.x);                            \
    errN.y = fmaf(-rnaN, fmaf(a1, d01T, p1), ksN.y);                            \
    errN.z = fmaf(-rnaN, fmaf(a2, d01T, p2), ksN.z);                            \
    errN.w = fmaf(-rnaN, fmaf(a3, d01T, p3), ksN.w);                            \
    float s = fmaf(errN.x, errN.x, fmaf(errN.y, errN.y,                         \
              fmaf(errN.z, errN.z, errN.w * errN.w)));                          \
    s = dpp_add<0x142>(s);                                                      \
    s = dpp_add<0x143>(s);                                                      \
    if (lane == 63) red_f[((t_ + 1) & 1) * 8 + w] = s;                          \
    __builtin_amdgcn_sched_barrier(0);                                          \
    /* deferred update (skipped when gate off; block-uniform branch) */         \
    if (gf != 0.f) {                                                            \
      m[0][0].x = fmaf(a0, KU[0].x, m[0][0].x);                                 \
      m[0][0].y = fmaf(a0, KU[0].y, m[0][0].y);                                 \
      m[0][0].z = fmaf(a0, KU[0].z, m[0][0].z);                                 \
      m[0][0].w = fmaf(a0, KU[0].w, m[0][0].w);                                 \
      m[0][1].x = fmaf(a0, KU[1].x, m[0][1].x);                                 \
      m[0][1].y = fmaf(a0, KU[1].y, m[0][1].y);                                 \
      m[0][1].z = fmaf(a0, KU[1].z, m[0][1].z);                                 \
      m[0][1].w = fmaf(a0, KU[1].w, m[0][1].w);                                 \
      m[1][0].x = fmaf(a1, KU[0].x, m[1][0].x);                                 \
      m[1][0].y = fmaf(a1, KU[0].y, m[1][0].y);                                 \
      m[1][0].z = fmaf(a1, KU[0].z, m[1][0].z);                                 \
      m[1][0].w = fmaf(a1, KU[0].w, m[1][0].w);                                 \
      m[1][1].x = fmaf(a1, KU[1].x, m[1][1].x);                                 \
      m[1][1].y = fmaf(a1, KU[1].y, m[1][1].y);                                 \
      m[1][1].z = fmaf(a1, KU[1].z, m[1][1].z);                                 \
      m[1][1].w = fmaf(a1, KU[1].w, m[1][1].w);                                 \
      m[2][0].x = fmaf(a2, KU[0].x, m[2][0].x);                                 \
      m[2][0].y = fmaf(a2, KU[0].y, m[2][0].y);                                 \
      m[2][0].z = fmaf(a2, KU[0].z, m[2][0].z);                                 \
      m[2][0].w = fmaf(a2, KU[0].w, m[2][0].w);                                 \
      m[2][1].x = fmaf(a2, KU[1].x, m[2][1].x);                                 \
      m[2][1].y = fmaf(a2, KU[1].y, m[2][1].y);                                 \
      m[2][1].z = fmaf(a2, KU[1].z, m[2][1].z);                                 \
      m[2][1].w = fmaf(a2, KU[1].w, m[2][1].w);                                 \
      m[3][0].x = fmaf(a3, KU[0].x, m[3][0].x);                                 \
      m[3][0].y = fmaf(a3, KU[0].y, m[3][0].y);                                 \
      m[3][0].z = fmaf(a3, KU[0].z, m[3][0].z);                                 \
      m[3][0].w = fmaf(a3, KU[0].w, m[3][0].w);                                 \
      m[3][1].x = fmaf(a3, KU[1].x, m[3][1].x);                                 \
      m[3][1].y = fmaf(a3, KU[1].y, m[3][1].y);                                 \
      m[3][1].z = fmaf(a3, KU[1].z, m[3][1].z);                                 \
      m[3][1].w = fmaf(a3, KU[1].w, m[3][1].w);                                 \
    }                                                                           \
    /* refill KU <- k_{t+2} chunk */                                            \
    KU[0] = shk4[(t_ + 2) * 32 + cg];                                           \
    KU[1] = shk4[(t_ + 2) * 32 + 16 + cg];                                      \
    __builtin_amdgcn_sched_barrier(0);                                          \
    /* outstanding: red write + 2 refills; lgkmcnt(2) retires the write,       \
       refill reads stay in flight ACROSS the barrier */                        \
    asm volatile("s_waitcnt lgkmcnt(2)" ::: "memory");                          \
    __builtin_amdgcn_sched_barrier(0);                                          \
    __builtin_amdgcn_s_barrier();                                               \
    errR = errN;                                                                \
  }

    for (int tt = 0; tt < 254; tt += 2) {
        REGION(tt,     kbE, kbO);
        REGION(tt + 1, kbO, kbE);
    }
#undef REGION

    // ---- epilogue: step 254, readout rows rg*4..+3 -> rd_ ----
    {
        float4 ra = ((const float4*)red_f)[0];   // parity (254&1)=0
        float4 rb = ((const float4*)red_f)[1];
        float E2 = ((ra.x + ra.y) + (ra.z + ra.w)) +
                   ((rb.x + rb.y) + (rb.z + rb.w));
        float gf = (E2 >= thr[254]) ? rna[254] : 0.f;
        float d01T = d01[254];
        float p0 = fma4(m[0][1], kbO[1], fma4(m[0][0], kbO[0], 0.f));
        float p1 = fma4(m[1][1], kbO[1], fma4(m[1][0], kbO[0], 0.f));
        float p2 = fma4(m[2][1], kbO[1], fma4(m[2][0], kbO[0], 0.f));
        float p3 = fma4(m[3][1], kbO[1], fma4(m[3][0], kbO[0], 0.f));
        p0 = group16_sum(p0); p1 = group16_sum(p1);
        p2 = group16_sum(p2); p3 = group16_sum(p3);
        float4 pre;
        pre.x = fmaf(gf * errR.x, d01T, p0);
        pre.y = fmaf(gf * errR.y, d01T, p1);
        pre.z = fmaf(gf * errR.z, d01T, p2);
        pre.w = fmaf(gf * errR.w, d01T, p3);
        if (cg == 0) *(float4*)&rd_[rg * 4] = pre;   // M_254·k_255
    }
    __syncthreads();

    // ---- fused out-projection: out = (rd @ Wr^T + br) @ Wo^T + bo ----
    {
        int i = tid >> 2, q = tid & 3;           // 4 threads per hidden elem
        const float4* Wr4 = (const float4*)Wr;
        const float4* rdv = (const float4*)rd_;
        float s = 0.f;
        #pragma unroll
        for (int u = 0; u < 8; ++u) s = fma4(rdv[q * 8 + u], Wr4[i * 32 + q * 8 + u], s);
        s += __shfl_xor(s, 1);
        s += __shfl_xor(s, 2);
        if (q == 0) r2_[i] = s + br[i];
    }
    __syncthreads();
    {
        int v = tid >> 1, h = tid & 1;           // 2 threads per output elem
        const float4* Wo4 = (const float4*)Wo;
        const float4* r2v = (const float4*)r2_;
        float s = 0.f;
        #pragma unroll
        for (int u = 0; u < 16; ++u) s = fma4(r2v[h * 16 + u], Wo4[v * 32 + h * 16 + u], s);
        s += __shfl_xor(s, 1);
        if (h == 0) out[b * 256 + v] = s + bo[v];
    }
}

// ---------------------------------------------------------------------------
extern "C" void kernel_launch(void* const* d_in, const int* in_sizes, int n_in,
                              void* d_out, int out_size, void* d_ws, size_t ws_size,
                              hipStream_t stream) {
    const int*   seq   = (const int*)  d_in[0];
    const float* embed = (const float*)d_in[1];
    const float* W1    = (const float*)d_in[2];
    const float* b1    = (const float*)d_in[3];
    const float* W2    = (const float*)d_in[4];
    const float* b2    = (const float*)d_in[5];
    const float* gamma = (const float*)d_in[6];
    const float* beta  = (const float*)d_in[7];
    const float* Wk    = (const float*)d_in[8];
    const float* Wr    = (const float*)d_in[9];
    const float* br    = (const float*)d_in[10];
    const float* Wo    = (const float*)d_in[11];
    const float* bo    = (const float*)d_in[12];

    float* Fbuf = (float*)d_ws;                      // 256*128 f32 = 128 KiB
    float* out  = (float*)d_out;

    // k_scan dynamic LDS: 128 KiB k-store + rna/thr/d01 + red + rd + r2
    const size_t scan_lds = 32768 * 4 + 3 * 256 * 4 + 16 * 4 + 2 * 128 * 4;

    k_vffn<<<VS_ / 4, 256, 0, stream>>>(embed, W1, b1, W2, b2, gamma, beta, Wk, Fbuf);
    k_scan<<<B_, 512, scan_lds, stream>>>(seq, Fbuf, Wr, br, Wo, bo, out);
}